// Round 1
// baseline (698.388 us; speedup 1.0000x reference)
//
#include <hip/hip_runtime.h>

typedef unsigned short u16;
typedef short bf16x8 __attribute__((ext_vector_type(8)));
typedef float f32x4 __attribute__((ext_vector_type(4)));

#define NNODES 32768

__device__ __forceinline__ u16 f2bf(float f) {
  union { float f; unsigned u; } v; v.f = f;
  unsigned r = v.u + 0x7fffu + ((v.u >> 16) & 1u);
  return (u16)(r >> 16);
}

__device__ __forceinline__ void gld_lds16(const u16* g, u16* l) {
  __builtin_amdgcn_global_load_lds(
      (const __attribute__((address_space(1))) void*)g,
      (__attribute__((address_space(3))) void*)l, 16, 0, 0);
}

// ---------------------------------------------------------------------------
// B^T GEMM: C[m,n] = sum_k A[m,k]*B[n,k], A:[M,K] bf16, B:[N,K] bf16.
// 128x128 tile, BK=32, 4 waves (each 64x64 => 4x4 of 16x16x32 MFMA).
// MODE 0: outb = bf16(acc+bias)                      (qkv)
// MODE 1: outf = acc+bias; outb = bf16(same)         (input proj -> h32+hb)
// MODE 2: outf = acc+bias+res                        (out-proj / ffn2 -> t32)
// MODE 3: outb = bf16(relu(acc+bias))                (ffn1)
// ---------------------------------------------------------------------------
template<int MODE>
__global__ __launch_bounds__(256) void gemm_bt(
    const u16* __restrict__ A, const u16* __restrict__ B,
    const float* __restrict__ bias, const float* __restrict__ res,
    float* __restrict__ outf, u16* __restrict__ outb,
    int N, int K)
{
  __shared__ u16 As[128 * 32];
  __shared__ u16 Bs[128 * 32];
  const int tid = threadIdx.x;
  const int wave = tid >> 6, lane = tid & 63;
  const int quad = lane >> 4, l16 = lane & 15;
  const int m0 = blockIdx.y * 128, n0 = blockIdx.x * 128;
  const int wm = (wave >> 1) * 64, wn = (wave & 1) * 64;
  const int r0 = tid >> 2, c0 = (tid & 3) * 8;

  const f32x4 zero = {0.f, 0.f, 0.f, 0.f};
  f32x4 acc[4][4];
#pragma unroll
  for (int i = 0; i < 4; i++)
#pragma unroll
    for (int j = 0; j < 4; j++) acc[i][j] = zero;

  const u16* Ap0 = A + (size_t)(m0 + r0) * K + c0;
  const u16* Ap1 = A + (size_t)(m0 + r0 + 64) * K + c0;
  const u16* Bp0 = B + (size_t)(n0 + r0) * K + c0;
  const u16* Bp1 = B + (size_t)(n0 + r0 + 64) * K + c0;
  u16* As0 = &As[tid * 8]; u16* As1 = &As[2048 + tid * 8];
  u16* Bs0 = &Bs[tid * 8]; u16* Bs1 = &Bs[2048 + tid * 8];

  for (int kt = 0; kt < K; kt += 32) {
    gld_lds16(Ap0 + kt, As0);
    gld_lds16(Ap1 + kt, As1);
    gld_lds16(Bp0 + kt, Bs0);
    gld_lds16(Bp1 + kt, Bs1);
    __syncthreads();
    bf16x8 a[4], b[4];
#pragma unroll
    for (int i = 0; i < 4; i++)
      a[i] = *(const bf16x8*)&As[(wm + i * 16 + l16) * 32 + quad * 8];
#pragma unroll
    for (int j = 0; j < 4; j++)
      b[j] = *(const bf16x8*)&Bs[(wn + j * 16 + l16) * 32 + quad * 8];
#pragma unroll
    for (int i = 0; i < 4; i++)
#pragma unroll
      for (int j = 0; j < 4; j++)
        acc[i][j] = __builtin_amdgcn_mfma_f32_16x16x32_bf16(a[i], b[j], acc[i][j], 0, 0, 0);
    __syncthreads();
  }

  float bj[4];
#pragma unroll
  for (int j = 0; j < 4; j++) bj[j] = bias[n0 + wn + j * 16 + l16];

#pragma unroll
  for (int i = 0; i < 4; i++) {
    const int Rb = m0 + wm + i * 16 + quad * 4;
#pragma unroll
    for (int r = 0; r < 4; r++) {
      const size_t ro = (size_t)(Rb + r) * N;
#pragma unroll
      for (int j = 0; j < 4; j++) {
        const int C = n0 + wn + j * 16 + l16;
        float v = acc[i][j][r] + bj[j];
        if (MODE == 0) {
          outb[ro + C] = f2bf(v);
        } else if (MODE == 1) {
          outf[ro + C] = v;
          outb[ro + C] = f2bf(v);
        } else if (MODE == 2) {
          outf[ro + C] = v + res[ro + C];
        } else {
          outb[ro + C] = f2bf(v > 0.f ? v : 0.f);
        }
      }
    }
  }
}

// ---------------------------------------------------------------------------
// Flash attention, one block per (graph, head). 256 nodes, DH=32.
// 4 waves x 64 q-rows; K/V processed in 4 chunks of 64 keys.
// ---------------------------------------------------------------------------
__global__ __launch_bounds__(256) void attn_k(
    const u16* __restrict__ qkv, u16* __restrict__ ob)
{
  __shared__ u16 Qs[256 * 32];     // [qrow][d]
  __shared__ u16 Ks[64 * 32];      // [key][d]
  __shared__ u16 Vts[32 * 72];     // [d][key] padded (+8) -> stride 144B
  __shared__ u16 Ps[4][64 * 72];   // per-wave P, padded

  const int tid = threadIdx.x;
  const int wave = tid >> 6, lane = tid & 63;
  const int quad = lane >> 4, l16 = lane & 15;
  const int g = blockIdx.x >> 3, h = blockIdx.x & 7;
  const int node0 = g << 8;
  const int qoff = h * 32, koff = 256 + h * 32, voff = 512 + h * 32;

#pragma unroll
  for (int p = 0; p < 4; p++) {
    int e = p * 2048 + tid * 8;
    int row = e >> 5, col = e & 31;
    *(bf16x8*)&Qs[e] = *(const bf16x8*)&qkv[(size_t)(node0 + row) * 768 + qoff + col];
  }

  float mst[4][4], lst[4][4];
  f32x4 o[4][2];
  const f32x4 zero = {0.f, 0.f, 0.f, 0.f};
#pragma unroll
  for (int i = 0; i < 4; i++) {
#pragma unroll
    for (int r = 0; r < 4; r++) { mst[i][r] = -1e30f; lst[i][r] = 0.f; }
    o[i][0] = zero; o[i][1] = zero;
  }
  const float sc = 0.17677669529663687f * 1.44269504088896340f; // 1/sqrt(32)*log2(e)

  const int lrow = tid >> 2, lcol = (tid & 3) * 8;
  for (int c = 0; c < 4; c++) {
    __syncthreads();
    {
      const size_t gb = (size_t)(node0 + c * 64 + lrow) * 768;
      *(bf16x8*)&Ks[lrow * 32 + lcol] = *(const bf16x8*)&qkv[gb + koff + lcol];
      bf16x8 vv = *(const bf16x8*)&qkv[gb + voff + lcol];
#pragma unroll
      for (int jj = 0; jj < 8; jj++) Vts[(lcol + jj) * 72 + lrow] = (u16)vv[jj];
    }
    __syncthreads();

    // S = Q K^T (this wave's 64 q-rows x 64 keys)
    f32x4 s[4][4];
    bf16x8 aq[4];
#pragma unroll
    for (int i = 0; i < 4; i++)
      aq[i] = *(const bf16x8*)&Qs[(wave * 64 + i * 16 + l16) * 32 + quad * 8];
#pragma unroll
    for (int j = 0; j < 4; j++) {
      bf16x8 bk = *(const bf16x8*)&Ks[(j * 16 + l16) * 32 + quad * 8];
#pragma unroll
      for (int i = 0; i < 4; i++)
        s[i][j] = __builtin_amdgcn_mfma_f32_16x16x32_bf16(aq[i], bk, zero, 0, 0, 0);
    }

    // online softmax; row = i*16 + quad*4 + r, reduce across the 16 l16 lanes
#pragma unroll
    for (int i = 0; i < 4; i++) {
#pragma unroll
      for (int r = 0; r < 4; r++) {
        float mx = fmaxf(fmaxf(s[i][0][r], s[i][1][r]), fmaxf(s[i][2][r], s[i][3][r]));
#pragma unroll
        for (int off = 1; off < 16; off <<= 1) mx = fmaxf(mx, __shfl_xor(mx, off, 64));
        float mloc = mx * sc;
        float mnew = fmaxf(mst[i][r], mloc);
        float alpha = exp2f(mst[i][r] - mnew);
        mst[i][r] = mnew;
        float rs = 0.f;
#pragma unroll
        for (int j = 0; j < 4; j++) {
          float p = exp2f(s[i][j][r] * sc - mnew);
          s[i][j][r] = p;
          rs += p;
        }
#pragma unroll
        for (int off = 1; off < 16; off <<= 1) rs += __shfl_xor(rs, off, 64);
        lst[i][r] = lst[i][r] * alpha + rs;
        o[i][0][r] *= alpha;
        o[i][1][r] *= alpha;
      }
    }

    // P (C-layout) -> LDS -> A-layout
#pragma unroll
    for (int i = 0; i < 4; i++)
#pragma unroll
      for (int r = 0; r < 4; r++) {
        const int prow = (i * 16 + quad * 4 + r) * 72;
#pragma unroll
        for (int j = 0; j < 4; j++)
          Ps[wave][prow + j * 16 + l16] = f2bf(s[i][j][r]);
      }

    // O += P V   (K=64 -> 2 mfma k-steps; V via transposed Vts)
#pragma unroll
    for (int i = 0; i < 4; i++) {
#pragma unroll
      for (int ks = 0; ks < 2; ks++) {
        bf16x8 ap = *(const bf16x8*)&Ps[wave][(i * 16 + l16) * 72 + ks * 32 + quad * 8];
#pragma unroll
        for (int n = 0; n < 2; n++) {
          bf16x8 bv = *(const bf16x8*)&Vts[(n * 16 + l16) * 72 + ks * 32 + quad * 8];
          o[i][n] = __builtin_amdgcn_mfma_f32_16x16x32_bf16(ap, bv, o[i][n], 0, 0, 0);
        }
      }
    }
  }

#pragma unroll
  for (int i = 0; i < 4; i++) {
    const int Rb = node0 + wave * 64 + i * 16 + quad * 4;
#pragma unroll
    for (int r = 0; r < 4; r++) {
      const float inv = 1.f / lst[i][r];
      const size_t ro = (size_t)(Rb + r) * 256;
#pragma unroll
      for (int n = 0; n < 2; n++)
        ob[ro + h * 32 + n * 16 + l16] = f2bf(o[i][n][r] * inv);
    }
  }
}

// ---------------------------------------------------------------------------
// LayerNorm over D=256. One wave per row (4 rows/block).
// FINAL=0: outf=LN(in)*ga+be (fp32) and outb=bf16(same)
// FINAL=1: outf = LN( LN(in)*ga+be )*ga2+be2   (fused last LN2 + final LN)
// ---------------------------------------------------------------------------
template<int FINAL>
__global__ __launch_bounds__(256) void ln_k(
    const float* __restrict__ in, const float* __restrict__ ga,
    const float* __restrict__ be, const float* __restrict__ ga2,
    const float* __restrict__ be2, float* __restrict__ outf,
    u16* __restrict__ outb)
{
  const int row = blockIdx.x * 4 + (threadIdx.x >> 6);
  const int lane = threadIdx.x & 63;
  const int c = lane * 4;
  const size_t off = (size_t)row * 256 + c;
  float4 x = *(const float4*)(in + off);
  float s = x.x + x.y + x.z + x.w;
  float q = x.x * x.x + x.y * x.y + x.z * x.z + x.w * x.w;
#pragma unroll
  for (int o = 1; o < 64; o <<= 1) { s += __shfl_xor(s, o, 64); q += __shfl_xor(q, o, 64); }
  float mu = s * 0.00390625f;
  float rs = rsqrtf(q * 0.00390625f - mu * mu + 1e-5f);
  float4 g4 = *(const float4*)(ga + c);
  float4 b4 = *(const float4*)(be + c);
  float4 y;
  y.x = (x.x - mu) * rs * g4.x + b4.x;
  y.y = (x.y - mu) * rs * g4.y + b4.y;
  y.z = (x.z - mu) * rs * g4.z + b4.z;
  y.w = (x.w - mu) * rs * g4.w + b4.w;
  if (FINAL == 0) {
    *(float4*)(outf + off) = y;
    unsigned long long pk =
        (unsigned long long)f2bf(y.x) | ((unsigned long long)f2bf(y.y) << 16) |
        ((unsigned long long)f2bf(y.z) << 32) | ((unsigned long long)f2bf(y.w) << 48);
    *(unsigned long long*)(outb + off) = pk;
  } else {
    float s2 = y.x + y.y + y.z + y.w;
    float q2 = y.x * y.x + y.y * y.y + y.z * y.z + y.w * y.w;
#pragma unroll
    for (int o = 1; o < 64; o <<= 1) { s2 += __shfl_xor(s2, o, 64); q2 += __shfl_xor(q2, o, 64); }
    float mu2 = s2 * 0.00390625f;
    float rs2 = rsqrtf(q2 * 0.00390625f - mu2 * mu2 + 1e-5f);
    float4 g24 = *(const float4*)(ga2 + c);
    float4 b24 = *(const float4*)(be2 + c);
    float4 z;
    z.x = (y.x - mu2) * rs2 * g24.x + b24.x;
    z.y = (y.y - mu2) * rs2 * g24.y + b24.y;
    z.z = (y.z - mu2) * rs2 * g24.z + b24.z;
    z.w = (y.w - mu2) * rs2 * g24.w + b24.w;
    *(float4*)(outf + off) = z;
  }
}

// ---------------------------------------------------------------------------
// fp32 -> bf16 convert for x + all weights (segment bounds are compile-time).
// ---------------------------------------------------------------------------
__global__ __launch_bounds__(256) void cvt_k(
    const float* __restrict__ s0, const float* __restrict__ s1,
    const float* __restrict__ s2, const float* __restrict__ s3,
    const float* __restrict__ s4, const float* __restrict__ s5,
    u16* __restrict__ d0, u16* __restrict__ d1, u16* __restrict__ d2,
    u16* __restrict__ d3, u16* __restrict__ d4, u16* __restrict__ d5)
{
  int t = (blockIdx.x * 256 + threadIdx.x) * 4;
  const float* s; u16* d; int off;
  if (t < 4194304)      { s = s0; d = d0; off = t; }
  else if (t < 4227072) { s = s1; d = d1; off = t - 4194304; }
  else if (t < 4816896) { s = s2; d = d2; off = t - 4227072; }
  else if (t < 5013504) { s = s3; d = d3; off = t - 4816896; }
  else if (t < 5406720) { s = s4; d = d4; off = t - 5013504; }
  else                  { s = s5; d = d5; off = t - 5406720; }
  float4 v = *(const float4*)(s + off);
  unsigned long long pk =
      (unsigned long long)f2bf(v.x) | ((unsigned long long)f2bf(v.y) << 16) |
      ((unsigned long long)f2bf(v.z) << 32) | ((unsigned long long)f2bf(v.w) << 48);
  *(unsigned long long*)(d + off) = pk;
}

extern "C" void kernel_launch(void* const* d_in, const int* in_sizes, int n_in,
                              void* d_out, int out_size, void* d_ws, size_t ws_size,
                              hipStream_t stream) {
  const float* x     = (const float*)d_in[0];
  const float* Wp    = (const float*)d_in[3];
  const float* bp    = (const float*)d_in[4];
  const float* in_w  = (const float*)d_in[5];
  const float* in_b  = (const float*)d_in[6];
  const float* out_w = (const float*)d_in[7];
  const float* out_b = (const float*)d_in[8];
  const float* n1_g  = (const float*)d_in[9];
  const float* n1_b  = (const float*)d_in[10];
  const float* W1    = (const float*)d_in[11];
  const float* b1    = (const float*)d_in[12];
  const float* W2    = (const float*)d_in[13];
  const float* b2    = (const float*)d_in[14];
  const float* n2_g  = (const float*)d_in[15];
  const float* n2_b  = (const float*)d_in[16];
  const float* ln_g  = (const float*)d_in[17];
  const float* ln_b  = (const float*)d_in[18];
  float* out = (float*)d_out;

  if (ws_size < 162594816u) return;  // fail loudly (out stays poisoned)

  char* ws = (char*)d_ws;
  float* h32 = (float*)(ws);                    // [32768,256] fp32 master
  float* t32 = (float*)(ws + 33554432);         // pre-LN scratch
  u16*   hb  = (u16*)(ws + 67108864);           // bf16 shadow of h
  u16*   ob  = (u16*)(ws + 83886080);           // attention out bf16
  u16*   mid = (u16*)(ws + 100663296);          // qkv [N,768] / ffn-mid [N,512]
  u16*   wb  = (u16*)(ws + 150994944);          // bf16 weights
  u16*   xb  = (u16*)(ws + 154206208);          // bf16 x

  u16* Wpb   = wb;
  u16* inwb  = wb + 32768;
  u16* outwb = wb + 622592;
  u16* W1b   = wb + 819200;
  u16* W2b   = wb + 1212416;

  cvt_k<<<5664, 256, 0, stream>>>(x, Wp, in_w, out_w, W1, W2,
                                  xb, Wpb, inwb, outwb, W1b, W2b);

  // h = x @ Wp^T + bp
  gemm_bt<1><<<dim3(2, 256), 256, 0, stream>>>(xb, Wpb, bp, nullptr, h32, hb, 256, 128);

  for (int l = 0; l < 3; l++) {
    // qkv
    gemm_bt<0><<<dim3(6, 256), 256, 0, stream>>>(hb, inwb + l * 196608, in_b + l * 768,
                                                 nullptr, nullptr, mid, 768, 256);
    // attention
    attn_k<<<1024, 256, 0, stream>>>(mid, ob);
    // out-proj + residual -> t32
    gemm_bt<2><<<dim3(2, 256), 256, 0, stream>>>(ob, outwb + l * 65536, out_b + l * 256,
                                                 h32, t32, nullptr, 256, 256);
    // LN1 -> h32, hb
    ln_k<0><<<8192, 256, 0, stream>>>(t32, n1_g + l * 256, n1_b + l * 256,
                                      nullptr, nullptr, h32, hb);
    // FFN1 (relu) -> mid
    gemm_bt<3><<<dim3(4, 256), 256, 0, stream>>>(hb, W1b + l * 131072, b1 + l * 512,
                                                 nullptr, nullptr, mid, 512, 256);
    // FFN2 + residual -> t32
    gemm_bt<2><<<dim3(2, 256), 256, 0, stream>>>(mid, W2b + l * 131072, b2 + l * 256,
                                                 h32, t32, nullptr, 256, 512);
    if (l < 2) {
      ln_k<0><<<8192, 256, 0, stream>>>(t32, n2_g + l * 256, n2_b + l * 256,
                                        nullptr, nullptr, h32, hb);
    } else {
      // fused: LN2(layer 3) then final LN -> d_out
      ln_k<1><<<8192, 256, 0, stream>>>(t32, n2_g + l * 256, n2_b + l * 256,
                                        ln_g, ln_b, out, nullptr);
    }
  }
}

// Round 2
// 663.135 us; speedup vs baseline: 1.0532x; 1.0532x over previous
//
#include <hip/hip_runtime.h>

typedef unsigned short u16;
typedef short bf16x8 __attribute__((ext_vector_type(8)));
typedef float f32x4 __attribute__((ext_vector_type(4)));

__device__ __forceinline__ u16 f2bf(float f) {
  union { float f; unsigned u; } v; v.f = f;
  unsigned r = v.u + 0x7fffu + ((v.u >> 16) & 1u);
  return (u16)(r >> 16);
}

__device__ __forceinline__ void gld_lds16(const u16* g, u16* l) {
  __builtin_amdgcn_global_load_lds(
      (const __attribute__((address_space(1))) void*)g,
      (__attribute__((address_space(3))) void*)l, 16, 0, 0);
}

// ---------------------------------------------------------------------------
// B^T GEMM: C[m,n] = sum_k A[m,k]*B[n,k], A:[M,K] bf16, B:[N,K] bf16.
// 128x128 tile, BK=32, 4 waves (each 64x64 => 4x4 of 16x16x32 MFMA).
// MODE 0: outb = bf16(acc+bias)                      (qkv)
// MODE 1: outf = acc+bias; outb = bf16(same)         (input proj -> h32+hb)
// MODE 2: outf = acc+bias+res                        (out-proj / ffn2 -> t32)
// MODE 3: outb = bf16(relu(acc+bias))                (ffn1)
// ---------------------------------------------------------------------------
template<int MODE>
__global__ __launch_bounds__(256) void gemm_bt(
    const u16* __restrict__ A, const u16* __restrict__ B,
    const float* __restrict__ bias, const float* __restrict__ res,
    float* __restrict__ outf, u16* __restrict__ outb,
    int N, int K)
{
  __shared__ u16 As[128 * 32];
  __shared__ u16 Bs[128 * 32];
  const int tid = threadIdx.x;
  const int wave = tid >> 6, lane = tid & 63;
  const int quad = lane >> 4, l16 = lane & 15;
  const int m0 = blockIdx.y * 128, n0 = blockIdx.x * 128;
  const int wm = (wave >> 1) * 64, wn = (wave & 1) * 64;
  const int r0 = tid >> 2, c0 = (tid & 3) * 8;

  const f32x4 zero = {0.f, 0.f, 0.f, 0.f};
  f32x4 acc[4][4];
#pragma unroll
  for (int i = 0; i < 4; i++)
#pragma unroll
    for (int j = 0; j < 4; j++) acc[i][j] = zero;

  const u16* Ap0 = A + (size_t)(m0 + r0) * K + c0;
  const u16* Ap1 = A + (size_t)(m0 + r0 + 64) * K + c0;
  const u16* Bp0 = B + (size_t)(n0 + r0) * K + c0;
  const u16* Bp1 = B + (size_t)(n0 + r0 + 64) * K + c0;
  u16* As0 = &As[tid * 8]; u16* As1 = &As[2048 + tid * 8];
  u16* Bs0 = &Bs[tid * 8]; u16* Bs1 = &Bs[2048 + tid * 8];

  for (int kt = 0; kt < K; kt += 32) {
    gld_lds16(Ap0 + kt, As0);
    gld_lds16(Ap1 + kt, As1);
    gld_lds16(Bp0 + kt, Bs0);
    gld_lds16(Bp1 + kt, Bs1);
    __syncthreads();
    bf16x8 a[4], b[4];
#pragma unroll
    for (int i = 0; i < 4; i++)
      a[i] = *(const bf16x8*)&As[(wm + i * 16 + l16) * 32 + quad * 8];
#pragma unroll
    for (int j = 0; j < 4; j++)
      b[j] = *(const bf16x8*)&Bs[(wn + j * 16 + l16) * 32 + quad * 8];
#pragma unroll
    for (int i = 0; i < 4; i++)
#pragma unroll
      for (int j = 0; j < 4; j++)
        acc[i][j] = __builtin_amdgcn_mfma_f32_16x16x32_bf16(a[i], b[j], acc[i][j], 0, 0, 0);
    __syncthreads();
  }

  float bj[4];
#pragma unroll
  for (int j = 0; j < 4; j++) bj[j] = bias[n0 + wn + j * 16 + l16];

#pragma unroll
  for (int i = 0; i < 4; i++) {
    const int Rb = m0 + wm + i * 16 + quad * 4;
#pragma unroll
    for (int r = 0; r < 4; r++) {
      const size_t ro = (size_t)(Rb + r) * N;
#pragma unroll
      for (int j = 0; j < 4; j++) {
        const int C = n0 + wn + j * 16 + l16;
        float v = acc[i][j][r] + bj[j];
        if (MODE == 0) {
          outb[ro + C] = f2bf(v);
        } else if (MODE == 1) {
          outf[ro + C] = v;
          outb[ro + C] = f2bf(v);
        } else if (MODE == 2) {
          outf[ro + C] = v + res[ro + C];
        } else {
          outb[ro + C] = f2bf(v > 0.f ? v : 0.f);
        }
      }
    }
  }
}

// ---------------------------------------------------------------------------
// Attention v2 ("S^T" scheme). Grid: 4096 blocks = (g:128, h:8, qc:4).
// Each block: 4 waves x 16 q-rows = 64 q. Per wave:
//   S^T = K.Q^T  (16 MFMA, K/Q direct from global)  -> lane owns scores of
//   one q-column -> one-pass softmax with only 4 shuffles.
//   O^T = V^T.P^T, P^T via wave-private swizzled LDS (no barrier),
//   V^T staged once per block in XOR-swizzled LDS (conflict-free b128).
// ---------------------------------------------------------------------------
__global__ __launch_bounds__(256) void attn_k(
    const u16* __restrict__ qkv, u16* __restrict__ ob)
{
  __shared__ u16 Vt[32 * 256];       // [d][key] swizzled: chunk^=(d&7)
  __shared__ u16 Pw[4][16 * 128];    // per-wave [q][keyloc] swizzled: chunk^=(q&7)

  const int tid = threadIdx.x;
  const int wave = tid >> 6, lane = tid & 63;
  const int quad = lane >> 4, l16 = lane & 15;
  const int bi = blockIdx.x;
  const int g = bi >> 5, h = (bi >> 2) & 7, qc = bi & 3;
  const int node0 = g << 8;
  const int qoff = h * 32, koff = 256 + h * 32, voff = 512 + h * 32;
  const int q0 = qc * 64 + wave * 16;

  // ---- stage V^T into LDS (coalesced u16 gathers, packed b128 writes) ----
  {
    const int d = lane & 31;
    const int kb2 = lane >> 5;  // 0..1
#pragma unroll
    for (int t = 0; t < 4; t++) {
      const int kbg = wave * 8 + t * 2 + kb2;  // key-block 0..31 (8 keys each)
      u16 vals[8];
#pragma unroll
      for (int i = 0; i < 8; i++)
        vals[i] = qkv[(size_t)(node0 + kbg * 8 + i) * 768 + voff + d];
      *(bf16x8*)&Vt[d * 256 + ((kbg ^ (d & 7)) << 3)] = *(bf16x8*)vals;
    }
  }

  // ---- Q fragment (B operand): Q[q=q0+l16][d=quad*8..+7] ----
  bf16x8 qf = *(const bf16x8*)&qkv[(size_t)(node0 + q0 + l16) * 768 + qoff + quad * 8];

  // ---- S^T = K.Q^T: s[ib] holds S^T[key=ib*16+quad*4+r][q=q0+l16] ----
  const f32x4 zero = {0.f, 0.f, 0.f, 0.f};
  f32x4 s[16];
#pragma unroll
  for (int ib = 0; ib < 16; ib++) {
    bf16x8 kf = *(const bf16x8*)&qkv[(size_t)(node0 + ib * 16 + l16) * 768 + koff + quad * 8];
    s[ib] = __builtin_amdgcn_mfma_f32_16x16x32_bf16(kf, qf, zero, 0, 0, 0);
  }

  __syncthreads();  // Vt ready

  // ---- one-pass softmax along this lane's q-column ----
  const float a = 0.17677669529663687f * 1.44269504088896340f;  // scale*log2(e)
  float mx = s[0][0];
#pragma unroll
  for (int ib = 0; ib < 16; ib++)
#pragma unroll
    for (int r = 0; r < 4; r++) mx = fmaxf(mx, s[ib][r]);
  mx = fmaxf(mx, __shfl_xor(mx, 16, 64));
  mx = fmaxf(mx, __shfl_xor(mx, 32, 64));
  const float M = mx * a;
  float lsum = 0.f;
#pragma unroll
  for (int ib = 0; ib < 16; ib++)
#pragma unroll
    for (int r = 0; r < 4; r++) {
      float p = exp2f(s[ib][r] * a - M);
      s[ib][r] = p;
      lsum += p;
    }
  lsum += __shfl_xor(lsum, 16, 64);
  lsum += __shfl_xor(lsum, 32, 64);

  // ---- O^T = V^T.P^T in two key-halves (wave-private P round-trip) ----
  f32x4 o[2] = {zero, zero};
  u16* pw = Pw[wave];
#pragma unroll
  for (int kh = 0; kh < 2; kh++) {
    // write P^T: q row = l16, keyloc = ib*16 + quad*4 + r (truncate-pack bf16)
#pragma unroll
    for (int ib = 0; ib < 8; ib++) {
      const f32x4 p = s[kh * 8 + ib];
      union { float f; unsigned u; } u0, u1, u2, u3;
      u0.f = p[0]; u1.f = p[1]; u2.f = p[2]; u3.f = p[3];
      uint2 pk;
      pk.x = __builtin_amdgcn_perm(u1.u, u0.u, 0x07060302u);
      pk.y = __builtin_amdgcn_perm(u3.u, u2.u, 0x07060302u);
      const int idx = l16 * 128 + (((2 * ib + (quad >> 1)) ^ (l16 & 7)) << 3) + (quad & 1) * 4;
      *(uint2*)&pw[idx] = pk;
    }
    // O^T += V^T . P^T  (4 key-blocks of 32)
#pragma unroll
    for (int kb = 0; kb < 4; kb++) {
      bf16x8 pf = *(const bf16x8*)&pw[l16 * 128 + (((4 * kb + quad) ^ (l16 & 7)) << 3)];
#pragma unroll
      for (int ib2 = 0; ib2 < 2; ib2++) {
        const int d = ib2 * 16 + l16;
        const int chunk = kh * 16 + 4 * kb + quad;
        bf16x8 vf = *(const bf16x8*)&Vt[d * 256 + ((chunk ^ (d & 7)) << 3)];
        o[ib2] = __builtin_amdgcn_mfma_f32_16x16x32_bf16(vf, pf, o[ib2], 0, 0, 0);
      }
    }
  }

  // ---- store: lane holds O^T[d=ib2*16+quad*4+r][q=q0+l16] ----
  const float inv = 1.f / lsum;
  const size_t rowbase = (size_t)(node0 + q0 + l16) * 256 + h * 32;
#pragma unroll
  for (int ib2 = 0; ib2 < 2; ib2++)
#pragma unroll
    for (int r = 0; r < 4; r++)
      ob[rowbase + ib2 * 16 + quad * 4 + r] = f2bf(o[ib2][r] * inv);
}

// ---------------------------------------------------------------------------
// LayerNorm over D=256. One wave per row (4 rows/block).
// FINAL=0: outf=LN(in)*ga+be (fp32) and outb=bf16(same)
// FINAL=1: outf = LN( LN(in)*ga+be )*ga2+be2   (fused last LN2 + final LN)
// ---------------------------------------------------------------------------
template<int FINAL>
__global__ __launch_bounds__(256) void ln_k(
    const float* __restrict__ in, const float* __restrict__ ga,
    const float* __restrict__ be, const float* __restrict__ ga2,
    const float* __restrict__ be2, float* __restrict__ outf,
    u16* __restrict__ outb)
{
  const int row = blockIdx.x * 4 + (threadIdx.x >> 6);
  const int lane = threadIdx.x & 63;
  const int c = lane * 4;
  const size_t off = (size_t)row * 256 + c;
  float4 x = *(const float4*)(in + off);
  float s = x.x + x.y + x.z + x.w;
  float q = x.x * x.x + x.y * x.y + x.z * x.z + x.w * x.w;
#pragma unroll
  for (int o = 1; o < 64; o <<= 1) { s += __shfl_xor(s, o, 64); q += __shfl_xor(q, o, 64); }
  float mu = s * 0.00390625f;
  float rs = rsqrtf(q * 0.00390625f - mu * mu + 1e-5f);
  float4 g4 = *(const float4*)(ga + c);
  float4 b4 = *(const float4*)(be + c);
  float4 y;
  y.x = (x.x - mu) * rs * g4.x + b4.x;
  y.y = (x.y - mu) * rs * g4.y + b4.y;
  y.z = (x.z - mu) * rs * g4.z + b4.z;
  y.w = (x.w - mu) * rs * g4.w + b4.w;
  if (FINAL == 0) {
    *(float4*)(outf + off) = y;
    unsigned long long pk =
        (unsigned long long)f2bf(y.x) | ((unsigned long long)f2bf(y.y) << 16) |
        ((unsigned long long)f2bf(y.z) << 32) | ((unsigned long long)f2bf(y.w) << 48);
    *(unsigned long long*)(outb + off) = pk;
  } else {
    float s2 = y.x + y.y + y.z + y.w;
    float q2 = y.x * y.x + y.y * y.y + y.z * y.z + y.w * y.w;
#pragma unroll
    for (int o = 1; o < 64; o <<= 1) { s2 += __shfl_xor(s2, o, 64); q2 += __shfl_xor(q2, o, 64); }
    float mu2 = s2 * 0.00390625f;
    float rs2 = rsqrtf(q2 * 0.00390625f - mu2 * mu2 + 1e-5f);
    float4 g24 = *(const float4*)(ga2 + c);
    float4 b24 = *(const float4*)(be2 + c);
    float4 z;
    z.x = (y.x - mu2) * rs2 * g24.x + b24.x;
    z.y = (y.y - mu2) * rs2 * g24.y + b24.y;
    z.z = (y.z - mu2) * rs2 * g24.z + b24.z;
    z.w = (y.w - mu2) * rs2 * g24.w + b24.w;
    *(float4*)(outf + off) = z;
  }
}

// ---------------------------------------------------------------------------
// fp32 -> bf16 convert for x + all weights (segment bounds are compile-time).
// ---------------------------------------------------------------------------
__global__ __launch_bounds__(256) void cvt_k(
    const float* __restrict__ s0, const float* __restrict__ s1,
    const float* __restrict__ s2, const float* __restrict__ s3,
    const float* __restrict__ s4, const float* __restrict__ s5,
    u16* __restrict__ d0, u16* __restrict__ d1, u16* __restrict__ d2,
    u16* __restrict__ d3, u16* __restrict__ d4, u16* __restrict__ d5)
{
  int t = (blockIdx.x * 256 + threadIdx.x) * 4;
  const float* s; u16* d; int off;
  if (t < 4194304)      { s = s0; d = d0; off = t; }
  else if (t < 4227072) { s = s1; d = d1; off = t - 4194304; }
  else if (t < 4816896) { s = s2; d = d2; off = t - 4227072; }
  else if (t < 5013504) { s = s3; d = d3; off = t - 4816896; }
  else if (t < 5406720) { s = s4; d = d4; off = t - 5013504; }
  else                  { s = s5; d = d5; off = t - 5406720; }
  float4 v = *(const float4*)(s + off);
  unsigned long long pk =
      (unsigned long long)f2bf(v.x) | ((unsigned long long)f2bf(v.y) << 16) |
      ((unsigned long long)f2bf(v.z) << 32) | ((unsigned long long)f2bf(v.w) << 48);
  *(unsigned long long*)(d + off) = pk;
}

extern "C" void kernel_launch(void* const* d_in, const int* in_sizes, int n_in,
                              void* d_out, int out_size, void* d_ws, size_t ws_size,
                              hipStream_t stream) {
  const float* x     = (const float*)d_in[0];
  const float* Wp    = (const float*)d_in[3];
  const float* bp    = (const float*)d_in[4];
  const float* in_w  = (const float*)d_in[5];
  const float* in_b  = (const float*)d_in[6];
  const float* out_w = (const float*)d_in[7];
  const float* out_b = (const float*)d_in[8];
  const float* n1_g  = (const float*)d_in[9];
  const float* n1_b  = (const float*)d_in[10];
  const float* W1    = (const float*)d_in[11];
  const float* b1    = (const float*)d_in[12];
  const float* W2    = (const float*)d_in[13];
  const float* b2    = (const float*)d_in[14];
  const float* n2_g  = (const float*)d_in[15];
  const float* n2_b  = (const float*)d_in[16];
  const float* ln_g  = (const float*)d_in[17];
  const float* ln_b  = (const float*)d_in[18];
  float* out = (float*)d_out;

  if (ws_size < 162594816u) return;  // fail loudly (out stays poisoned)

  char* ws = (char*)d_ws;
  float* h32 = (float*)(ws);                    // [32768,256] fp32 master
  float* t32 = (float*)(ws + 33554432);         // pre-LN scratch
  u16*   hb  = (u16*)(ws + 67108864);           // bf16 shadow of h
  u16*   ob  = (u16*)(ws + 83886080);           // attention out bf16
  u16*   mid = (u16*)(ws + 100663296);          // qkv [N,768] / ffn-mid [N,512]
  u16*   wb  = (u16*)(ws + 150994944);          // bf16 weights
  u16*   xb  = (u16*)(ws + 154206208);          // bf16 x

  u16* Wpb   = wb;
  u16* inwb  = wb + 32768;
  u16* outwb = wb + 622592;
  u16* W1b   = wb + 819200;
  u16* W2b   = wb + 1212416;

  cvt_k<<<5664, 256, 0, stream>>>(x, Wp, in_w, out_w, W1, W2,
                                  xb, Wpb, inwb, outwb, W1b, W2b);

  // h = x @ Wp^T + bp
  gemm_bt<1><<<dim3(2, 256), 256, 0, stream>>>(xb, Wpb, bp, nullptr, h32, hb, 256, 128);

  for (int l = 0; l < 3; l++) {
    // qkv
    gemm_bt<0><<<dim3(6, 256), 256, 0, stream>>>(hb, inwb + l * 196608, in_b + l * 768,
                                                 nullptr, nullptr, mid, 768, 256);
    // attention
    attn_k<<<4096, 256, 0, stream>>>(mid, ob);
    // out-proj + residual -> t32
    gemm_bt<2><<<dim3(2, 256), 256, 0, stream>>>(ob, outwb + l * 65536, out_b + l * 256,
                                                 h32, t32, nullptr, 256, 256);
    // LN1 -> h32, hb
    ln_k<0><<<8192, 256, 0, stream>>>(t32, n1_g + l * 256, n1_b + l * 256,
                                      nullptr, nullptr, h32, hb);
    // FFN1 (relu) -> mid
    gemm_bt<3><<<dim3(4, 256), 256, 0, stream>>>(hb, W1b + l * 131072, b1 + l * 512,
                                                 nullptr, nullptr, mid, 512, 256);
    // FFN2 + residual -> t32
    gemm_bt<2><<<dim3(2, 256), 256, 0, stream>>>(mid, W2b + l * 131072, b2 + l * 256,
                                                 h32, t32, nullptr, 256, 512);
    if (l < 2) {
      ln_k<0><<<8192, 256, 0, stream>>>(t32, n2_g + l * 256, n2_b + l * 256,
                                        nullptr, nullptr, h32, hb);
    } else {
      // fused: LN2(layer 3) then final LN -> d_out
      ln_k<1><<<8192, 256, 0, stream>>>(t32, n2_g + l * 256, n2_b + l * 256,
                                        ln_g, ln_b, out, nullptr);
    }
  }
}

// Round 4
// 629.908 us; speedup vs baseline: 1.1087x; 1.0527x over previous
//
#include <hip/hip_runtime.h>

typedef unsigned short u16;
typedef short bf16x8 __attribute__((ext_vector_type(8)));
typedef float f32x4 __attribute__((ext_vector_type(4)));

__device__ __forceinline__ u16 f2bf(float f) {
  union { float f; unsigned u; } v; v.f = f;
  unsigned r = v.u + 0x7fffu + ((v.u >> 16) & 1u);
  return (u16)(r >> 16);
}

__device__ __forceinline__ void gld_lds16(const u16* g, u16* l) {
  __builtin_amdgcn_global_load_lds(
      (const __attribute__((address_space(1))) void*)g,
      (__attribute__((address_space(3))) void*)l, 16, 0, 0);
}

// ---------------------------------------------------------------------------
// B^T GEMM: C[m,n] = sum_k A[m,k]*B[n,k], A:[M,K] bf16, B:[N,K] bf16.
// 128x128 tile, BK=32, 4 waves (each 64x64 => 4x4 of 16x16x32 MFMA).
// MODE 0: outb = bf16(acc+bias)                      (qkv)
// MODE 1: outf = acc+bias; outb = bf16(same)         (input proj -> h32+hb)
// MODE 2: outf = acc+bias+res                        (out-proj / ffn2 -> t32)
// MODE 3: outb = bf16(relu(acc+bias))                (ffn1)
// ---------------------------------------------------------------------------
template<int MODE>
__global__ __launch_bounds__(256) void gemm_bt(
    const u16* __restrict__ A, const u16* __restrict__ B,
    const float* __restrict__ bias, const float* __restrict__ res,
    float* __restrict__ outf, u16* __restrict__ outb,
    int N, int K)
{
  __shared__ u16 As[128 * 32];
  __shared__ u16 Bs[128 * 32];
  const int tid = threadIdx.x;
  const int wave = tid >> 6, lane = tid & 63;
  const int quad = lane >> 4, l16 = lane & 15;
  const int m0 = blockIdx.y * 128, n0 = blockIdx.x * 128;
  const int wm = (wave >> 1) * 64, wn = (wave & 1) * 64;
  const int r0 = tid >> 2, c0 = (tid & 3) * 8;

  const f32x4 zero = {0.f, 0.f, 0.f, 0.f};
  f32x4 acc[4][4];
#pragma unroll
  for (int i = 0; i < 4; i++)
#pragma unroll
    for (int j = 0; j < 4; j++) acc[i][j] = zero;

  const u16* Ap0 = A + (size_t)(m0 + r0) * K + c0;
  const u16* Ap1 = A + (size_t)(m0 + r0 + 64) * K + c0;
  const u16* Bp0 = B + (size_t)(n0 + r0) * K + c0;
  const u16* Bp1 = B + (size_t)(n0 + r0 + 64) * K + c0;
  u16* As0 = &As[tid * 8]; u16* As1 = &As[2048 + tid * 8];
  u16* Bs0 = &Bs[tid * 8]; u16* Bs1 = &Bs[2048 + tid * 8];

  for (int kt = 0; kt < K; kt += 32) {
    gld_lds16(Ap0 + kt, As0);
    gld_lds16(Ap1 + kt, As1);
    gld_lds16(Bp0 + kt, Bs0);
    gld_lds16(Bp1 + kt, Bs1);
    __syncthreads();
    bf16x8 a[4], b[4];
#pragma unroll
    for (int i = 0; i < 4; i++)
      a[i] = *(const bf16x8*)&As[(wm + i * 16 + l16) * 32 + quad * 8];
#pragma unroll
    for (int j = 0; j < 4; j++)
      b[j] = *(const bf16x8*)&Bs[(wn + j * 16 + l16) * 32 + quad * 8];
#pragma unroll
    for (int i = 0; i < 4; i++)
#pragma unroll
      for (int j = 0; j < 4; j++)
        acc[i][j] = __builtin_amdgcn_mfma_f32_16x16x32_bf16(a[i], b[j], acc[i][j], 0, 0, 0);
    __syncthreads();
  }

  float bj[4];
#pragma unroll
  for (int j = 0; j < 4; j++) bj[j] = bias[n0 + wn + j * 16 + l16];

#pragma unroll
  for (int i = 0; i < 4; i++) {
    const int Rb = m0 + wm + i * 16 + quad * 4;
#pragma unroll
    for (int r = 0; r < 4; r++) {
      const size_t ro = (size_t)(Rb + r) * N;
#pragma unroll
      for (int j = 0; j < 4; j++) {
        const int C = n0 + wn + j * 16 + l16;
        float v = acc[i][j][r] + bj[j];
        if (MODE == 0) {
          outb[ro + C] = f2bf(v);
        } else if (MODE == 1) {
          outf[ro + C] = v;
          outb[ro + C] = f2bf(v);
        } else if (MODE == 2) {
          outf[ro + C] = v + res[ro + C];
        } else {
          outb[ro + C] = f2bf(v > 0.f ? v : 0.f);
        }
      }
    }
  }
}

// ---------------------------------------------------------------------------
// Attention v3. Grid: 1024 blocks = (g:128, h:8); K and V^T staged in LDS
// ONCE per block, then 4 q-chunks of 64 processed with no barriers.
// Per wave/qc: S^T = K.Q^T (16 MFMA), one-pass softmax (4 shuffles),
// O^T = V^T.P^T (16 MFMA) with wave-private swizzled P round-trip.
// LDS 48KB -> 3 blocks/CU.
// ---------------------------------------------------------------------------
__global__ __launch_bounds__(256) void attn_k(
    const u16* __restrict__ qkv, u16* __restrict__ ob)
{
  __shared__ u16 Ks[256 * 32];       // [key][d] row-major
  __shared__ u16 Vt[32 * 256];       // [d][key] swizzled: chunk^=(d&7)
  __shared__ u16 Pw[4][16 * 128];    // per-wave [q][keyloc] swizzled: chunk^=(q&7)

  const int tid = threadIdx.x;
  const int wave = tid >> 6, lane = tid & 63;
  const int quad = lane >> 4, l16 = lane & 15;
  const int g = blockIdx.x >> 3, h = blockIdx.x & 7;
  const int node0 = g << 8;
  const int qoff = h * 32, koff = 256 + h * 32, voff = 512 + h * 32;

  // ---- stage K rows into LDS (global_load_lds, 4 passes x 4KB) ----
  {
    const int kr = tid >> 2, kc = (tid & 3) * 8;
    const u16* Kp = qkv + (size_t)(node0 + kr) * 768 + koff + kc;
    u16* Kd = &Ks[tid * 8];
#pragma unroll
    for (int pass = 0; pass < 4; pass++)
      gld_lds16(Kp + (size_t)pass * 64 * 768, Kd + pass * 2048);
  }

  // ---- stage V^T into LDS (coalesced u16 gathers, packed b128 writes) ----
  {
    const int d = lane & 31;
    const int kb2 = lane >> 5;  // 0..1
#pragma unroll
    for (int t = 0; t < 4; t++) {
      const int kbg = wave * 8 + t * 2 + kb2;  // key-block 0..31 (8 keys each)
      u16 vals[8];
#pragma unroll
      for (int i = 0; i < 8; i++)
        vals[i] = qkv[(size_t)(node0 + kbg * 8 + i) * 768 + voff + d];
      *(bf16x8*)&Vt[d * 256 + ((kbg ^ (d & 7)) << 3)] = *(bf16x8*)vals;
    }
  }

  __syncthreads();  // Ks + Vt ready; no further barriers

  const f32x4 zero = {0.f, 0.f, 0.f, 0.f};
  const float a = 0.17677669529663687f * 1.44269504088896340f;  // scale*log2(e)
  u16* pw = Pw[wave];

  for (int qc = 0; qc < 4; qc++) {
    const int q0 = qc * 64 + wave * 16;

    // Q fragment (B operand): Q[q=q0+l16][d=quad*8..+7]
    bf16x8 qf = *(const bf16x8*)&qkv[(size_t)(node0 + q0 + l16) * 768 + qoff + quad * 8];

    // S^T = K.Q^T: s[ib] holds S^T[key=ib*16+quad*4+r][q=q0+l16]
    f32x4 s[16];
#pragma unroll
    for (int ib = 0; ib < 16; ib++) {
      bf16x8 kf = *(const bf16x8*)&Ks[(ib * 16 + l16) * 32 + quad * 8];
      s[ib] = __builtin_amdgcn_mfma_f32_16x16x32_bf16(kf, qf, zero, 0, 0, 0);
    }

    // one-pass softmax along this lane's q-column
    float mx = s[0][0];
#pragma unroll
    for (int ib = 0; ib < 16; ib++)
#pragma unroll
      for (int r = 0; r < 4; r++) mx = fmaxf(mx, s[ib][r]);
    mx = fmaxf(mx, __shfl_xor(mx, 16, 64));
    mx = fmaxf(mx, __shfl_xor(mx, 32, 64));
    const float M = mx * a;
    float lsum = 0.f;
#pragma unroll
    for (int ib = 0; ib < 16; ib++)
#pragma unroll
      for (int r = 0; r < 4; r++) {
        float p = exp2f(s[ib][r] * a - M);
        s[ib][r] = p;
        lsum += p;
      }
    lsum += __shfl_xor(lsum, 16, 64);
    lsum += __shfl_xor(lsum, 32, 64);

    // O^T = V^T.P^T in two key-halves (wave-private P round-trip)
    f32x4 o[2] = {zero, zero};
#pragma unroll
    for (int kh = 0; kh < 2; kh++) {
      // write P^T: q row = l16, keyloc = ib*16 + quad*4 + r (truncate-pack bf16)
#pragma unroll
      for (int ib = 0; ib < 8; ib++) {
        const f32x4 p = s[kh * 8 + ib];
        union { float f; unsigned u; } u0, u1, u2, u3;
        u0.f = p[0]; u1.f = p[1]; u2.f = p[2]; u3.f = p[3];
        uint2 pk;
        pk.x = __builtin_amdgcn_perm(u1.u, u0.u, 0x07060302u);
        pk.y = __builtin_amdgcn_perm(u3.u, u2.u, 0x07060302u);
        const int idx = l16 * 128 + (((2 * ib + (quad >> 1)) ^ (l16 & 7)) << 3) + (quad & 1) * 4;
        *(uint2*)&pw[idx] = pk;
      }
      // O^T += V^T . P^T  (4 key-blocks of 32)
#pragma unroll
      for (int kb = 0; kb < 4; kb++) {
        bf16x8 pf = *(const bf16x8*)&pw[l16 * 128 + (((4 * kb + quad) ^ (l16 & 7)) << 3)];
#pragma unroll
        for (int ib2 = 0; ib2 < 2; ib2++) {
          const int d = ib2 * 16 + l16;
          const int chunk = kh * 16 + 4 * kb + quad;
          bf16x8 vf = *(const bf16x8*)&Vt[d * 256 + ((chunk ^ (d & 7)) << 3)];
          o[ib2] = __builtin_amdgcn_mfma_f32_16x16x32_bf16(vf, pf, o[ib2], 0, 0, 0);
        }
      }
    }

    // store: lane holds O^T[d=ib2*16+quad*4+r][q=q0+l16]
    const float inv = 1.f / lsum;
    const size_t rowbase = (size_t)(node0 + q0 + l16) * 256 + h * 32;
#pragma unroll
    for (int ib2 = 0; ib2 < 2; ib2++)
#pragma unroll
      for (int r = 0; r < 4; r++)
        ob[rowbase + ib2 * 16 + quad * 4 + r] = f2bf(o[ib2][r] * inv);
  }
}

// ---------------------------------------------------------------------------
// LayerNorm over D=256. One wave per row (4 rows/block).
// FINAL=0: outf=LN(in)*ga+be (fp32) and outb=bf16(same)
// FINAL=1: outf = LN( LN(in)*ga+be )*ga2+be2   (fused last LN2 + final LN)
// ---------------------------------------------------------------------------
template<int FINAL>
__global__ __launch_bounds__(256) void ln_k(
    const float* __restrict__ in, const float* __restrict__ ga,
    const float* __restrict__ be, const float* __restrict__ ga2,
    const float* __restrict__ be2, float* __restrict__ outf,
    u16* __restrict__ outb)
{
  const int row = blockIdx.x * 4 + (threadIdx.x >> 6);
  const int lane = threadIdx.x & 63;
  const int c = lane * 4;
  const size_t off = (size_t)row * 256 + c;
  float4 x = *(const float4*)(in + off);
  float s = x.x + x.y + x.z + x.w;
  float q = x.x * x.x + x.y * x.y + x.z * x.z + x.w * x.w;
#pragma unroll
  for (int o = 1; o < 64; o <<= 1) { s += __shfl_xor(s, o, 64); q += __shfl_xor(q, o, 64); }
  float mu = s * 0.00390625f;
  float rs = rsqrtf(q * 0.00390625f - mu * mu + 1e-5f);
  float4 g4 = *(const float4*)(ga + c);
  float4 b4 = *(const float4*)(be + c);
  float4 y;
  y.x = (x.x - mu) * rs * g4.x + b4.x;
  y.y = (x.y - mu) * rs * g4.y + b4.y;
  y.z = (x.z - mu) * rs * g4.z + b4.z;
  y.w = (x.w - mu) * rs * g4.w + b4.w;
  if (FINAL == 0) {
    *(float4*)(outf + off) = y;
    unsigned long long pk =
        (unsigned long long)f2bf(y.x) | ((unsigned long long)f2bf(y.y) << 16) |
        ((unsigned long long)f2bf(y.z) << 32) | ((unsigned long long)f2bf(y.w) << 48);
    *(unsigned long long*)(outb + off) = pk;
  } else {
    float s2 = y.x + y.y + y.z + y.w;
    float q2 = y.x * y.x + y.y * y.y + y.z * y.z + y.w * y.w;
#pragma unroll
    for (int o = 1; o < 64; o <<= 1) { s2 += __shfl_xor(s2, o, 64); q2 += __shfl_xor(q2, o, 64); }
    float mu2 = s2 * 0.00390625f;
    float rs2 = rsqrtf(q2 * 0.00390625f - mu2 * mu2 + 1e-5f);
    float4 g24 = *(const float4*)(ga2 + c);
    float4 b24 = *(const float4*)(be2 + c);
    float4 z;
    z.x = (y.x - mu2) * rs2 * g24.x + b24.x;
    z.y = (y.y - mu2) * rs2 * g24.y + b24.y;
    z.z = (y.z - mu2) * rs2 * g24.z + b24.z;
    z.w = (y.w - mu2) * rs2 * g24.w + b24.w;
    *(float4*)(outf + off) = z;
  }
}

// ---------------------------------------------------------------------------
// fp32 -> bf16 convert for x + all weights (segment bounds are compile-time).
// ---------------------------------------------------------------------------
__global__ __launch_bounds__(256) void cvt_k(
    const float* __restrict__ s0, const float* __restrict__ s1,
    const float* __restrict__ s2, const float* __restrict__ s3,
    const float* __restrict__ s4, const float* __restrict__ s5,
    u16* __restrict__ d0, u16* __restrict__ d1, u16* __restrict__ d2,
    u16* __restrict__ d3, u16* __restrict__ d4, u16* __restrict__ d5)
{
  int t = (blockIdx.x * 256 + threadIdx.x) * 4;
  const float* s; u16* d; int off;
  if (t < 4194304)      { s = s0; d = d0; off = t; }
  else if (t < 4227072) { s = s1; d = d1; off = t - 4194304; }
  else if (t < 4816896) { s = s2; d = d2; off = t - 4227072; }
  else if (t < 5013504) { s = s3; d = d3; off = t - 4816896; }
  else if (t < 5406720) { s = s4; d = d4; off = t - 5013504; }
  else                  { s = s5; d = d5; off = t - 5406720; }
  float4 v = *(const float4*)(s + off);
  unsigned long long pk =
      (unsigned long long)f2bf(v.x) | ((unsigned long long)f2bf(v.y) << 16) |
      ((unsigned long long)f2bf(v.z) << 32) | ((unsigned long long)f2bf(v.w) << 48);
  *(unsigned long long*)(d + off) = pk;
}

extern "C" void kernel_launch(void* const* d_in, const int* in_sizes, int n_in,
                              void* d_out, int out_size, void* d_ws, size_t ws_size,
                              hipStream_t stream) {
  const float* x     = (const float*)d_in[0];
  const float* Wp    = (const float*)d_in[3];
  const float* bp    = (const float*)d_in[4];
  const float* in_w  = (const float*)d_in[5];
  const float* in_b  = (const float*)d_in[6];
  const float* out_w = (const float*)d_in[7];
  const float* out_b = (const float*)d_in[8];
  const float* n1_g  = (const float*)d_in[9];
  const float* n1_b  = (const float*)d_in[10];
  const float* W1    = (const float*)d_in[11];
  const float* b1    = (const float*)d_in[12];
  const float* W2    = (const float*)d_in[13];
  const float* b2    = (const float*)d_in[14];
  const float* n2_g  = (const float*)d_in[15];
  const float* n2_b  = (const float*)d_in[16];
  const float* ln_g  = (const float*)d_in[17];
  const float* ln_b  = (const float*)d_in[18];
  float* out = (float*)d_out;

  if (ws_size < 162594816u) return;  // fail loudly (out stays poisoned)

  char* ws = (char*)d_ws;
  float* h32 = (float*)(ws);                    // [32768,256] fp32 master
  float* t32 = (float*)(ws + 33554432);         // pre-LN scratch
  u16*   hb  = (u16*)(ws + 67108864);           // bf16 shadow of h
  u16*   ob  = (u16*)(ws + 83886080);           // attention out bf16
  u16*   mid = (u16*)(ws + 100663296);          // qkv [N,768] / ffn-mid [N,512]
  u16*   wb  = (u16*)(ws + 150994944);          // bf16 weights
  u16*   xb  = (u16*)(ws + 154206208);          // bf16 x

  u16* Wpb   = wb;
  u16* inwb  = wb + 32768;
  u16* outwb = wb + 622592;
  u16* W1b   = wb + 819200;
  u16* W2b   = wb + 1212416;

  cvt_k<<<5664, 256, 0, stream>>>(x, Wp, in_w, out_w, W1, W2,
                                  xb, Wpb, inwb, outwb, W1b, W2b);

  // h = x @ Wp^T + bp
  gemm_bt<1><<<dim3(2, 256), 256, 0, stream>>>(xb, Wpb, bp, nullptr, h32, hb, 256, 128);

  for (int l = 0; l < 3; l++) {
    // qkv
    gemm_bt<0><<<dim3(6, 256), 256, 0, stream>>>(hb, inwb + l * 196608, in_b + l * 768,
                                                 nullptr, nullptr, mid, 768, 256);
    // attention
    attn_k<<<1024, 256, 0, stream>>>(mid, ob);
    // out-proj + residual -> t32
    gemm_bt<2><<<dim3(2, 256), 256, 0, stream>>>(ob, outwb + l * 65536, out_b + l * 256,
                                                 h32, t32, nullptr, 256, 256);
    // LN1 -> h32, hb
    ln_k<0><<<8192, 256, 0, stream>>>(t32, n1_g + l * 256, n1_b + l * 256,
                                      nullptr, nullptr, h32, hb);
    // FFN1 (relu) -> mid
    gemm_bt<3><<<dim3(4, 256), 256, 0, stream>>>(hb, W1b + l * 131072, b1 + l * 512,
                                                 nullptr, nullptr, mid, 512, 256);
    // FFN2 + residual -> t32
    gemm_bt<2><<<dim3(2, 256), 256, 0, stream>>>(mid, W2b + l * 131072, b2 + l * 256,
                                                 h32, t32, nullptr, 256, 512);
    if (l < 2) {
      ln_k<0><<<8192, 256, 0, stream>>>(t32, n2_g + l * 256, n2_b + l * 256,
                                        nullptr, nullptr, h32, hb);
    } else {
      // fused: LN2(layer 3) then final LN -> d_out
      ln_k<1><<<8192, 256, 0, stream>>>(t32, n2_g + l * 256, n2_b + l * 256,
                                        ln_g, ln_b, out, nullptr);
    }
  }
}